// Round 12
// baseline (541.028 us; speedup 1.0000x reference)
//
#include <hip/hip_runtime.h>

#define NNODES 100000
#define NEDGES 1600000
#define NBUC 196      // ceil(100000/512)
#define BWID 512
#define PB 256        // partition grid blocks

__device__ __forceinline__ float asf(int v) { return __int_as_float(v); }

// ---------------- pass 1: per-bucket edge counts (LDS hist -> 392 hot global adds/block) ----------------
__global__ __launch_bounds__(256) void count_k(const int* __restrict__ src, const int* __restrict__ dst,
                                               int* __restrict__ gd, int* __restrict__ gs) {
    __shared__ int hd[NBUC], hs_[NBUC];
    int t = threadIdx.x;
    for (int i = t; i < NBUC; i += 256) { hd[i] = 0; hs_[i] = 0; }
    __syncthreads();
    for (int e = blockIdx.x * 256 + t; e < NEDGES; e += PB * 256) {
        atomicAdd(&hd[dst[e] >> 9], 1);
        atomicAdd(&hs_[src[e] >> 9], 1);
    }
    __syncthreads();
    for (int i = t; i < NBUC; i += 256) {
        if (hd[i])  atomicAdd(&gd[i], hd[i]);
        if (hs_[i]) atomicAdd(&gs[i], hs_[i]);
    }
}

// ---------------- pass 2: exclusive scan counts -> FLAT bases; init global cursors to bases ----------------
__global__ __launch_bounds__(256) void scanb_k(const int* __restrict__ gd, const int* __restrict__ gs,
                                               int* __restrict__ based, int* __restrict__ bases,
                                               int* __restrict__ curD, int* __restrict__ curS) {
    __shared__ int sa[256], sb[256];
    int t = threadIdx.x;
    int va = (t < NBUC) ? gd[t] : 0;
    int vb = (t < NBUC) ? gs[t] : 0;
    sa[t] = va; sb[t] = vb;
    __syncthreads();
    for (int off = 1; off < 256; off <<= 1) {
        int ua = (t >= off) ? sa[t - off] : 0;
        int ub = (t >= off) ? sb[t - off] : 0;
        __syncthreads();
        sa[t] += ua; sb[t] += ub;
        __syncthreads();
    }
    if (t < NBUC) {
        int ea = sa[t] - va, eb = sb[t] - vb;
        based[t] = ea; curD[t] = ea;        // cursors start at flat bases
        bases[t] = eb; curS[t] = eb;
    }
}

// ---------------- pass 3: partition edges to flat positions ----------------
__global__ __launch_bounds__(256) void part2_k(const int* __restrict__ src, const int* __restrict__ dst,
                                               const float* __restrict__ ew,
                                               int* __restrict__ curD, int* __restrict__ curS,
                                               int2* __restrict__ bufD, int2* __restrict__ bufS) {
    __shared__ int hd[NBUC], hs_[NBUC], bd[NBUC], bs_[NBUC], cd[NBUC], cs_[NBUC];
    int t = threadIdx.x;
    for (int i = t; i < NBUC; i += 256) { hd[i] = 0; hs_[i] = 0; cd[i] = 0; cs_[i] = 0; }
    __syncthreads();
    int start = blockIdx.x * 256 + t;
    for (int e = start; e < NEDGES; e += PB * 256) {
        atomicAdd(&hd[dst[e] >> 9], 1);
        atomicAdd(&hs_[src[e] >> 9], 1);
    }
    __syncthreads();
    for (int i = t; i < NBUC; i += 256) {
        bd[i]  = hd[i]  ? atomicAdd(&curD[i], hd[i])  : 0;   // flat disjoint range per block
        bs_[i] = hs_[i] ? atomicAdd(&curS[i], hs_[i]) : 0;
    }
    __syncthreads();
    for (int e = start; e < NEDGES; e += PB * 256) {
        int s = src[e], d = dst[e];
        int w = __float_as_int(ew[e]);
        int kb = d >> 9;
        int pos = bd[kb] + atomicAdd(&cd[kb], 1);
        bufD[pos] = make_int2((s << 9) | (d & 511), w);
        int sb = s >> 9;
        int pos2 = bs_[sb] + atomicAdd(&cs_[sb], 1);
        bufS[pos2] = make_int2(s & 511, w);
    }
}

// ---------------- per-src-bucket degree + dinv (LDS atomics only) ----------------
__global__ __launch_bounds__(512) void deg_k(const int2* __restrict__ bufS, const int* __restrict__ bases,
                                             const int* __restrict__ gs, float* __restrict__ dinv) {
    __shared__ float dl[BWID];
    int bk = blockIdx.x, t = threadIdx.x;
    dl[t] = 0.f;
    __syncthreads();
    int base = bases[bk], cb = gs[bk];
    for (int i = t; i < cb; i += 512) {
        int2 p = bufS[base + i];
        atomicAdd(&dl[p.x], asf(p.y));
    }
    __syncthreads();
    int id = bk * BWID + t;
    if (id < NNODES) {
        float dd = dl[t];
        dinv[id] = (dd > 0.f) ? rsqrtf(fmaxf(dd, 1e-12f)) : 0.f;
    }
}

// ---------------- per-dst-bucket CSR build: LDS hist + scan + scatter ----------------
__global__ __launch_bounds__(512) void csr_k(const int2* __restrict__ bufD, const int* __restrict__ based,
                                             const int* __restrict__ gd, const float* __restrict__ dinv,
                                             int* __restrict__ rowptr, int2* __restrict__ csr) {
    __shared__ float dl[BWID];
    __shared__ int ex[BWID], sc[BWID], cur[BWID];
    int bk = blockIdx.x, t = threadIdx.x;
    int g0 = bk * BWID;
    { int id = g0 + t; dl[t] = (id < NNODES) ? dinv[id] : 0.f; }
    ex[t] = 0; cur[t] = 0;
    __syncthreads();
    int base = based[bk], cb = gd[bk];
    for (int i = t; i < cb; i += 512) atomicAdd(&ex[bufD[base + i].x & 511], 1);
    __syncthreads();
    int v = ex[t];
    sc[t] = v;
    __syncthreads();
    for (int off = 1; off < BWID; off <<= 1) {
        int u = (t >= off) ? sc[t - off] : 0;
        __syncthreads();
        sc[t] += u;
        __syncthreads();
    }
    int excl = sc[t] - v;
    ex[t] = excl;
    int id = g0 + t;
    if (id <= NNODES) rowptr[id] = base + excl;   // bucket 195 t=160 writes rowptr[N]=E
    __syncthreads();
    for (int i = t; i < cb; i += 512) {
        int2 p = bufD[base + i];
        int dlow = p.x & 511, s = p.x >> 9;
        float nw = -dinv[s] * asf(p.y) * dl[dlow];
        int pos = base + ex[dlow] + atomicAdd(&cur[dlow], 1);
        csr[pos] = make_int2(s, __float_as_int(nw));
    }
}

// ---------------- layer 1: gather (8 chains, VECTOR loads) + dense (64->64) + relu + y/z epilogue ----------------
// one wave per node; 4 waves/block; h never stored.
// NOTE: rs/re deliberately kept in VGPRs (no readfirstlane) — uniform csr[i] indices get
// scalarized into serialized s_load chains (R11: VGPR=20, 315us vs R1's VGPR=32, 147us).
__global__ __launch_bounds__(256, 8) void layer1_k(const float* __restrict__ feat,
                                                   const int* __restrict__ rowptr,
                                                   const int2* __restrict__ csr,
                                                   const float* __restrict__ W0, const float* __restrict__ W1,
                                                   const float* __restrict__ b,
                                                   const float* __restrict__ W2_0, const float* __restrict__ W2_1,
                                                   float* __restrict__ yout, float* __restrict__ zout) {
    __shared__ float tx[4][192];
    int wid = threadIdx.x >> 6;
    int lane = threadIdx.x & 63;
    int n = blockIdx.x * 4 + wid;   // grid = 25000 -> exactly NNODES

    int rs = rowptr[n], re = rowptr[n + 1];   // vector loads (proven @147us R1)

    float tx0 = feat[n * 64 + lane];

    float a0=0.f,a1=0.f,a2=0.f,a3=0.f,a4=0.f,a5=0.f,a6=0.f,a7=0.f;
    int i = rs;
    for (; i + 8 <= re; i += 8) {
        int2 p0 = csr[i],   p1 = csr[i+1], p2 = csr[i+2], p3 = csr[i+3];
        int2 p4 = csr[i+4], p5 = csr[i+5], p6 = csr[i+6], p7 = csr[i+7];
        a0 = fmaf(asf(p0.y), feat[p0.x * 64 + lane], a0);
        a1 = fmaf(asf(p1.y), feat[p1.x * 64 + lane], a1);
        a2 = fmaf(asf(p2.y), feat[p2.x * 64 + lane], a2);
        a3 = fmaf(asf(p3.y), feat[p3.x * 64 + lane], a3);
        a4 = fmaf(asf(p4.y), feat[p4.x * 64 + lane], a4);
        a5 = fmaf(asf(p5.y), feat[p5.x * 64 + lane], a5);
        a6 = fmaf(asf(p6.y), feat[p6.x * 64 + lane], a6);
        a7 = fmaf(asf(p7.y), feat[p7.x * 64 + lane], a7);
    }
    for (; i < re; ++i) {
        int2 p = csr[i];
        a0 = fmaf(asf(p.y), feat[p.x * 64 + lane], a0);
    }
    float acc = ((a0 + a1) + (a2 + a3)) + ((a4 + a5) + (a6 + a7));

    tx[wid][lane] = tx0;
    tx[wid][64 + lane] = acc;
    // wave-private LDS slice: no __syncthreads needed (proven)

    float hj = b[lane];
    const float4* tp = (const float4*)&tx[wid][0];
    #pragma unroll
    for (int q = 0; q < 16; q++) {
        float4 a = tp[q];
        hj = fmaf(a.x, W0[(4 * q + 0) * 64 + lane], hj);
        hj = fmaf(a.y, W0[(4 * q + 1) * 64 + lane], hj);
        hj = fmaf(a.z, W0[(4 * q + 2) * 64 + lane], hj);
        hj = fmaf(a.w, W0[(4 * q + 3) * 64 + lane], hj);
    }
    #pragma unroll
    for (int q = 0; q < 16; q++) {
        float4 a = tp[16 + q];
        hj = fmaf(a.x, W1[(4 * q + 0) * 64 + lane], hj);
        hj = fmaf(a.y, W1[(4 * q + 1) * 64 + lane], hj);
        hj = fmaf(a.z, W1[(4 * q + 2) * 64 + lane], hj);
        hj = fmaf(a.w, W1[(4 * q + 3) * 64 + lane], hj);
    }
    float h = fmaxf(hj, 0.f);

    // epilogue: y = h @ W2_1 (layer2 gathers this) and z0 = h @ W2_0 (layer2 dense term)
    tx[wid][128 + lane] = h;
    int j = lane & 15, g = lane >> 4;
    float py = 0.f, pz = 0.f;
    #pragma unroll
    for (int t2 = 0; t2 < 16; t2++) {
        int d = g * 16 + t2;
        float hv = tx[wid][128 + d];
        py = fmaf(hv, W2_1[d * 16 + j], py);
        pz = fmaf(hv, W2_0[d * 16 + j], pz);
    }
    py += __shfl_xor(py, 16, 64);
    py += __shfl_xor(py, 32, 64);
    pz += __shfl_xor(pz, 16, 64);
    pz += __shfl_xor(pz, 32, 64);
    if (g == 0) yout[n * 16 + j] = py;
    else if (g == 1) zout[n * 16 + j] = pz;
}

// ---------------- layer 2: 16-wide gather of y + z0 + bias + log_softmax ----------------
// readfirstlane OK here: csr index rs+g is lane-divergent -> loads stay vector (proven)
__global__ __launch_bounds__(256, 8) void layer2_k(const float* __restrict__ y,
                                                   const float* __restrict__ z0,
                                                   const int* __restrict__ rowptr,
                                                   const int2* __restrict__ csr,
                                                   const float* __restrict__ b,
                                                   float* __restrict__ out) {
    int wid = threadIdx.x >> 6, lane = threadIdx.x & 63;
    int n = blockIdx.x * 4 + wid;

    int rs = __builtin_amdgcn_readfirstlane(rowptr[n]);
    int re = __builtin_amdgcn_readfirstlane(rowptr[n + 1]);

    int j = lane & 15, g = lane >> 4;   // group g handles edges rs+g, rs+g+4, ...

    float A0 = 0.f, A1 = 0.f;
    int i = rs + g;
    for (; i + 4 < re; i += 8) {
        int2 p0 = csr[i], p1 = csr[i + 4];
        A0 = fmaf(asf(p0.y), y[p0.x * 16 + j], A0);
        A1 = fmaf(asf(p1.y), y[p1.x * 16 + j], A1);
    }
    if (i < re) {
        int2 p = csr[i];
        A0 = fmaf(asf(p.y), y[p.x * 16 + j], A0);
    }
    float part = A0 + A1;
    part += __shfl_xor(part, 16, 64);
    part += __shfl_xor(part, 32, 64);
    float oc = part + z0[n * 16 + j] + b[j];

    float mx = oc;
    #pragma unroll
    for (int mk = 1; mk < 16; mk <<= 1) mx = fmaxf(mx, __shfl_xor(mx, mk, 64));
    float ex = expf(oc - mx);
    float s = ex;
    #pragma unroll
    for (int mk = 1; mk < 16; mk <<= 1) s += __shfl_xor(s, mk, 64);
    float r = oc - mx - logf(s);
    if (g == 0) out[n * 16 + j] = r;
}

extern "C" void kernel_launch(void* const* d_in, const int* in_sizes, int n_in,
                              void* d_out, int out_size, void* d_ws, size_t ws_size,
                              hipStream_t stream) {
    const float* feat = (const float*)d_in[0];
    const int*   eidx = (const int*)d_in[1];
    const float* ew   = (const float*)d_in[2];
    const float* W1_0 = (const float*)d_in[3];
    const float* W1_1 = (const float*)d_in[4];
    const float* b1   = (const float*)d_in[5];
    const float* W2_0 = (const float*)d_in[6];
    const float* W2_1 = (const float*)d_in[7];
    const float* b2   = (const float*)d_in[8];
    float* out = (float*)d_out;

    const int* srcv = eidx;            // edge_index[0]
    const int* dstv = eidx + NEDGES;   // edge_index[1]

    // workspace carve — ~39.2 MB (< 47.2 MB proven)
    int*   gd     = (int*)d_ws;                    // 256
    int*   gs     = gd + 256;                      // 256
    int*   based  = gs + 256;                      // 256
    int*   bases  = based + 256;                   // 256
    int*   curD   = bases + 256;                   // 256
    int*   curS   = curD + 256;                    // 256
    float* dinv   = (float*)(curS + 256);          // N
    int*   rowptr = (int*)(dinv + NNODES);         // N+1
    int*   padp   = rowptr + NNODES + 1;           // +1 pad -> int2 (8B) alignment
    int2*  bufD   = (int2*)(padp + 1);             // E
    int2*  bufS   = bufD + NEDGES;                 // E (csr aliases this after deg_k)
    float* ybuf   = (float*)(bufS + NEDGES);       // N*16
    float* zbuf   = ybuf + NNODES * 16;            // N*16
    int2*  csr    = bufS;

    hipMemsetAsync(gd, 0, 512 * sizeof(int), stream);   // gd + gs only

    count_k<<<PB, 256, 0, stream>>>(srcv, dstv, gd, gs);
    scanb_k<<<1, 256, 0, stream>>>(gd, gs, based, bases, curD, curS);
    part2_k<<<PB, 256, 0, stream>>>(srcv, dstv, ew, curD, curS, bufD, bufS);
    deg_k<<<NBUC, 512, 0, stream>>>(bufS, bases, gs, dinv);
    csr_k<<<NBUC, 512, 0, stream>>>(bufD, based, gd, dinv, rowptr, csr);

    layer1_k<<<NNODES / 4, 256, 0, stream>>>(feat, rowptr, csr, W1_0, W1_1, b1, W2_0, W2_1, ybuf, zbuf);
    layer2_k<<<NNODES / 4, 256, 0, stream>>>(ybuf, zbuf, rowptr, csr, b2, out);
}

// Round 13
// 366.171 us; speedup vs baseline: 1.4775x; 1.4775x over previous
//
#include <hip/hip_runtime.h>

#define NNODES 100000
#define NEDGES 1600000
#define NBUC 196      // ceil(100000/512)
#define BWID 512
#define PB 256        // partition grid blocks

__device__ __forceinline__ float asf(int v) { return __int_as_float(v); }

// ---------------- pass 1: per-bucket edge counts (LDS hist -> 392 hot global adds/block) ----------------
__global__ __launch_bounds__(256) void count_k(const int* __restrict__ src, const int* __restrict__ dst,
                                               int* __restrict__ gd, int* __restrict__ gs) {
    __shared__ int hd[NBUC], hs_[NBUC];
    int t = threadIdx.x;
    for (int i = t; i < NBUC; i += 256) { hd[i] = 0; hs_[i] = 0; }
    __syncthreads();
    for (int e = blockIdx.x * 256 + t; e < NEDGES; e += PB * 256) {
        atomicAdd(&hd[dst[e] >> 9], 1);
        atomicAdd(&hs_[src[e] >> 9], 1);
    }
    __syncthreads();
    for (int i = t; i < NBUC; i += 256) {
        if (hd[i])  atomicAdd(&gd[i], hd[i]);
        if (hs_[i]) atomicAdd(&gs[i], hs_[i]);
    }
}

// ---------------- pass 2: exclusive scan counts -> FLAT bases; init global cursors to bases ----------------
__global__ __launch_bounds__(256) void scanb_k(const int* __restrict__ gd, const int* __restrict__ gs,
                                               int* __restrict__ based, int* __restrict__ bases,
                                               int* __restrict__ curD, int* __restrict__ curS) {
    __shared__ int sa[256], sb[256];
    int t = threadIdx.x;
    int va = (t < NBUC) ? gd[t] : 0;
    int vb = (t < NBUC) ? gs[t] : 0;
    sa[t] = va; sb[t] = vb;
    __syncthreads();
    for (int off = 1; off < 256; off <<= 1) {
        int ua = (t >= off) ? sa[t - off] : 0;
        int ub = (t >= off) ? sb[t - off] : 0;
        __syncthreads();
        sa[t] += ua; sb[t] += ub;
        __syncthreads();
    }
    if (t < NBUC) {
        int ea = sa[t] - va, eb = sb[t] - vb;
        based[t] = ea; curD[t] = ea;        // cursors start at flat bases
        bases[t] = eb; curS[t] = eb;
    }
}

// ---------------- pass 3: partition edges to flat positions ----------------
__global__ __launch_bounds__(256) void part2_k(const int* __restrict__ src, const int* __restrict__ dst,
                                               const float* __restrict__ ew,
                                               int* __restrict__ curD, int* __restrict__ curS,
                                               int2* __restrict__ bufD, int2* __restrict__ bufS) {
    __shared__ int hd[NBUC], hs_[NBUC], bd[NBUC], bs_[NBUC], cd[NBUC], cs_[NBUC];
    int t = threadIdx.x;
    for (int i = t; i < NBUC; i += 256) { hd[i] = 0; hs_[i] = 0; cd[i] = 0; cs_[i] = 0; }
    __syncthreads();
    int start = blockIdx.x * 256 + t;
    for (int e = start; e < NEDGES; e += PB * 256) {
        atomicAdd(&hd[dst[e] >> 9], 1);
        atomicAdd(&hs_[src[e] >> 9], 1);
    }
    __syncthreads();
    for (int i = t; i < NBUC; i += 256) {
        bd[i]  = hd[i]  ? atomicAdd(&curD[i], hd[i])  : 0;   // flat disjoint range per block
        bs_[i] = hs_[i] ? atomicAdd(&curS[i], hs_[i]) : 0;
    }
    __syncthreads();
    for (int e = start; e < NEDGES; e += PB * 256) {
        int s = src[e], d = dst[e];
        int w = __float_as_int(ew[e]);
        int kb = d >> 9;
        int pos = bd[kb] + atomicAdd(&cd[kb], 1);
        bufD[pos] = make_int2((s << 9) | (d & 511), w);
        int sb = s >> 9;
        int pos2 = bs_[sb] + atomicAdd(&cs_[sb], 1);
        bufS[pos2] = make_int2(s & 511, w);
    }
}

// ---------------- per-src-bucket degree + dinv (LDS atomics only) ----------------
__global__ __launch_bounds__(512) void deg_k(const int2* __restrict__ bufS, const int* __restrict__ bases,
                                             const int* __restrict__ gs, float* __restrict__ dinv) {
    __shared__ float dl[BWID];
    int bk = blockIdx.x, t = threadIdx.x;
    dl[t] = 0.f;
    __syncthreads();
    int base = bases[bk], cb = gs[bk];
    for (int i = t; i < cb; i += 512) {
        int2 p = bufS[base + i];
        atomicAdd(&dl[p.x], asf(p.y));
    }
    __syncthreads();
    int id = bk * BWID + t;
    if (id < NNODES) {
        float dd = dl[t];
        dinv[id] = (dd > 0.f) ? rsqrtf(fmaxf(dd, 1e-12f)) : 0.f;
    }
}

// ---------------- per-dst-bucket CSR build: LDS hist + scan + scatter ----------------
__global__ __launch_bounds__(512) void csr_k(const int2* __restrict__ bufD, const int* __restrict__ based,
                                             const int* __restrict__ gd, const float* __restrict__ dinv,
                                             int* __restrict__ rowptr, int2* __restrict__ csr) {
    __shared__ float dl[BWID];
    __shared__ int ex[BWID], sc[BWID], cur[BWID];
    int bk = blockIdx.x, t = threadIdx.x;
    int g0 = bk * BWID;
    { int id = g0 + t; dl[t] = (id < NNODES) ? dinv[id] : 0.f; }
    ex[t] = 0; cur[t] = 0;
    __syncthreads();
    int base = based[bk], cb = gd[bk];
    for (int i = t; i < cb; i += 512) atomicAdd(&ex[bufD[base + i].x & 511], 1);
    __syncthreads();
    int v = ex[t];
    sc[t] = v;
    __syncthreads();
    for (int off = 1; off < BWID; off <<= 1) {
        int u = (t >= off) ? sc[t - off] : 0;
        __syncthreads();
        sc[t] += u;
        __syncthreads();
    }
    int excl = sc[t] - v;
    ex[t] = excl;
    int id = g0 + t;
    if (id <= NNODES) rowptr[id] = base + excl;   // bucket 195 t=160 writes rowptr[N]=E
    __syncthreads();
    for (int i = t; i < cb; i += 512) {
        int2 p = bufD[base + i];
        int dlow = p.x & 511, s = p.x >> 9;
        float nw = -dinv[s] * asf(p.y) * dl[dlow];
        int pos = base + ex[dlow] + atomicAdd(&cur[dlow], 1);
        csr[pos] = make_int2(s, __float_as_int(nw));
    }
}

// ---------------- layer 1: gather (EXACT R1-proven 4-chain form) + dense (64->64) + relu + y/z epilogue ----------------
// one wave per node; 4 waves/block; h never stored.
// R12 post-mortem: 8-chain unroll made the compiler pick a low-register serialized
// schedule (VGPR 20-28, 315-337us). 4 chains + rfl = proven 147us @ VGPR 32.
__global__ __launch_bounds__(256, 8) void layer1_k(const float* __restrict__ feat,
                                                   const int* __restrict__ rowptr,
                                                   const int2* __restrict__ csr,
                                                   const float* __restrict__ W0, const float* __restrict__ W1,
                                                   const float* __restrict__ b,
                                                   const float* __restrict__ W2_0, const float* __restrict__ W2_1,
                                                   float* __restrict__ yout, float* __restrict__ zout) {
    __shared__ float tx[4][192];
    int wid = threadIdx.x >> 6;
    int lane = threadIdx.x & 63;
    int n = blockIdx.x * 4 + wid;   // grid = 25000 -> exactly NNODES

    int rs = __builtin_amdgcn_readfirstlane(rowptr[n]);
    int re = __builtin_amdgcn_readfirstlane(rowptr[n + 1]);

    float tx0 = feat[n * 64 + lane];

    // gather: 4 independent accumulator chains (PROVEN @147us R1)
    float a0 = 0.f, a1 = 0.f, a2 = 0.f, a3 = 0.f;
    int i = rs;
    for (; i + 4 <= re; i += 4) {
        int2 p0 = csr[i], p1 = csr[i + 1], p2 = csr[i + 2], p3 = csr[i + 3];
        a0 = fmaf(asf(p0.y), feat[p0.x * 64 + lane], a0);
        a1 = fmaf(asf(p1.y), feat[p1.x * 64 + lane], a1);
        a2 = fmaf(asf(p2.y), feat[p2.x * 64 + lane], a2);
        a3 = fmaf(asf(p3.y), feat[p3.x * 64 + lane], a3);
    }
    for (; i < re; ++i) {
        int2 p = csr[i];
        a0 = fmaf(asf(p.y), feat[p.x * 64 + lane], a0);
    }
    float acc = (a0 + a1) + (a2 + a3);

    tx[wid][lane] = tx0;
    tx[wid][64 + lane] = acc;
    // wave-private LDS slice: no __syncthreads needed (proven)

    float hj = b[lane];
    const float4* tp = (const float4*)&tx[wid][0];
    #pragma unroll
    for (int q = 0; q < 16; q++) {
        float4 a = tp[q];
        hj = fmaf(a.x, W0[(4 * q + 0) * 64 + lane], hj);
        hj = fmaf(a.y, W0[(4 * q + 1) * 64 + lane], hj);
        hj = fmaf(a.z, W0[(4 * q + 2) * 64 + lane], hj);
        hj = fmaf(a.w, W0[(4 * q + 3) * 64 + lane], hj);
    }
    #pragma unroll
    for (int q = 0; q < 16; q++) {
        float4 a = tp[16 + q];
        hj = fmaf(a.x, W1[(4 * q + 0) * 64 + lane], hj);
        hj = fmaf(a.y, W1[(4 * q + 1) * 64 + lane], hj);
        hj = fmaf(a.z, W1[(4 * q + 2) * 64 + lane], hj);
        hj = fmaf(a.w, W1[(4 * q + 3) * 64 + lane], hj);
    }
    float h = fmaxf(hj, 0.f);

    // epilogue: y = h @ W2_1 (layer2 gathers this) and z0 = h @ W2_0 (layer2 dense term)
    tx[wid][128 + lane] = h;
    int j = lane & 15, g = lane >> 4;
    float py = 0.f, pz = 0.f;
    #pragma unroll
    for (int t2 = 0; t2 < 16; t2++) {
        int d = g * 16 + t2;
        float hv = tx[wid][128 + d];
        py = fmaf(hv, W2_1[d * 16 + j], py);
        pz = fmaf(hv, W2_0[d * 16 + j], pz);
    }
    py += __shfl_xor(py, 16, 64);
    py += __shfl_xor(py, 32, 64);
    pz += __shfl_xor(pz, 16, 64);
    pz += __shfl_xor(pz, 32, 64);
    if (g == 0) yout[n * 16 + j] = py;
    else if (g == 1) zout[n * 16 + j] = pz;
}

// ---------------- layer 2: 16-wide gather of y + z0 + bias + log_softmax ----------------
__global__ __launch_bounds__(256, 8) void layer2_k(const float* __restrict__ y,
                                                   const float* __restrict__ z0,
                                                   const int* __restrict__ rowptr,
                                                   const int2* __restrict__ csr,
                                                   const float* __restrict__ b,
                                                   float* __restrict__ out) {
    int wid = threadIdx.x >> 6, lane = threadIdx.x & 63;
    int n = blockIdx.x * 4 + wid;

    int rs = __builtin_amdgcn_readfirstlane(rowptr[n]);
    int re = __builtin_amdgcn_readfirstlane(rowptr[n + 1]);

    int j = lane & 15, g = lane >> 4;   // group g handles edges rs+g, rs+g+4, ...

    float A0 = 0.f, A1 = 0.f;
    int i = rs + g;
    for (; i + 4 < re; i += 8) {
        int2 p0 = csr[i], p1 = csr[i + 4];
        A0 = fmaf(asf(p0.y), y[p0.x * 16 + j], A0);
        A1 = fmaf(asf(p1.y), y[p1.x * 16 + j], A1);
    }
    if (i < re) {
        int2 p = csr[i];
        A0 = fmaf(asf(p.y), y[p.x * 16 + j], A0);
    }
    float part = A0 + A1;
    part += __shfl_xor(part, 16, 64);
    part += __shfl_xor(part, 32, 64);
    float oc = part + z0[n * 16 + j] + b[j];

    float mx = oc;
    #pragma unroll
    for (int mk = 1; mk < 16; mk <<= 1) mx = fmaxf(mx, __shfl_xor(mx, mk, 64));
    float ex = expf(oc - mx);
    float s = ex;
    #pragma unroll
    for (int mk = 1; mk < 16; mk <<= 1) s += __shfl_xor(s, mk, 64);
    float r = oc - mx - logf(s);
    if (g == 0) out[n * 16 + j] = r;
}

extern "C" void kernel_launch(void* const* d_in, const int* in_sizes, int n_in,
                              void* d_out, int out_size, void* d_ws, size_t ws_size,
                              hipStream_t stream) {
    const float* feat = (const float*)d_in[0];
    const int*   eidx = (const int*)d_in[1];
    const float* ew   = (const float*)d_in[2];
    const float* W1_0 = (const float*)d_in[3];
    const float* W1_1 = (const float*)d_in[4];
    const float* b1   = (const float*)d_in[5];
    const float* W2_0 = (const float*)d_in[6];
    const float* W2_1 = (const float*)d_in[7];
    const float* b2   = (const float*)d_in[8];
    float* out = (float*)d_out;

    const int* srcv = eidx;            // edge_index[0]
    const int* dstv = eidx + NEDGES;   // edge_index[1]

    // workspace carve — ~39.2 MB (< 47.2 MB proven)
    int*   gd     = (int*)d_ws;                    // 256
    int*   gs     = gd + 256;                      // 256
    int*   based  = gs + 256;                      // 256
    int*   bases  = based + 256;                   // 256
    int*   curD   = bases + 256;                   // 256
    int*   curS   = curD + 256;                    // 256
    float* dinv   = (float*)(curS + 256);          // N
    int*   rowptr = (int*)(dinv + NNODES);         // N+1
    int*   padp   = rowptr + NNODES + 1;           // +1 pad -> int2 (8B) alignment
    int2*  bufD   = (int2*)(padp + 1);             // E
    int2*  bufS   = bufD + NEDGES;                 // E (csr aliases this after deg_k)
    float* ybuf   = (float*)(bufS + NEDGES);       // N*16
    float* zbuf   = ybuf + NNODES * 16;            // N*16
    int2*  csr    = bufS;

    hipMemsetAsync(gd, 0, 512 * sizeof(int), stream);   // gd + gs only

    count_k<<<PB, 256, 0, stream>>>(srcv, dstv, gd, gs);
    scanb_k<<<1, 256, 0, stream>>>(gd, gs, based, bases, curD, curS);
    part2_k<<<PB, 256, 0, stream>>>(srcv, dstv, ew, curD, curS, bufD, bufS);
    deg_k<<<NBUC, 512, 0, stream>>>(bufS, bases, gs, dinv);
    csr_k<<<NBUC, 512, 0, stream>>>(bufD, based, gd, dinv, rowptr, csr);

    layer1_k<<<NNODES / 4, 256, 0, stream>>>(feat, rowptr, csr, W1_0, W1_1, b1, W2_0, W2_1, ybuf, zbuf);
    layer2_k<<<NNODES / 4, 256, 0, stream>>>(ybuf, zbuf, rowptr, csr, b2, out);
}